// Round 6
// baseline (453.652 us; speedup 1.0000x reference)
//
#include <hip/hip_runtime.h>

#define NELEM 500000
#define NDOF 500000
#define HID 64
#define NT 31250                 // wave-tiles: 2M GP-rows / 64 (exact, no tail rows)
#define NBLK 768                 // 3 blocks/CU * 256 CU
#define NWAVE (NBLK * 4)

typedef _Float16 half2v __attribute__((ext_vector_type(2)));
typedef _Float16 half8v __attribute__((ext_vector_type(8)));
typedef float float4v __attribute__((ext_vector_type(4)));

// lambda = 2*log2(e): prescaled into W1,b1,W2,b2 so tanh needs no multiply.
#define LAM 2.885390081777927f

__device__ __forceinline__ half2v pk(float a, float b) {
    return __builtin_bit_cast(half2v, __builtin_amdgcn_cvt_pkrtz(a, b));
}
// tanh(z) with y = LAM*z prescaled. exp2(+-inf) saturates correctly.
__device__ __forceinline__ float tanh2(float y) {
    float e = __builtin_amdgcn_exp2f(y);
    float r = __builtin_amdgcn_rcpf(e + 1.0f);
    return fmaf(-2.0f, r, 1.0f);
}
__device__ __forceinline__ float fdot2(half2v a, half2v b, float c) {
    return __builtin_amdgcn_fdot2(a, b, c, false);
}

// ds_swizzle BitMode: src = ((lane&AND)|OR)^XOR within 32-lane halves.
//   quad broadcast j: 0x1C,0x3C,0x5C,0x7C ; xor16: 0x401F
#define SWZF(x, pat) __builtin_bit_cast(float, \
    __builtin_amdgcn_ds_swizzle(__builtin_bit_cast(int, (x)), (pat)))

// ---- setup kernel 1: pack per-lane weight fragments into workspace ----
__global__ __launch_bounds__(64, 1) void pack_weights(
    const float* __restrict__ W1, const float* __restrict__ b1,
    const float* __restrict__ W2, uint4* __restrict__ ws)
{
    const int lane = threadIdx.x & 63;
    const int quad = lane >> 4, l15 = lane & 15;
    union { uint4 q[4]; uint u[16]; } WU;
    union { uint4 q[4]; float f[16]; } BU;
#pragma unroll
    for (int f = 0; f < 2; f++)
#pragma unroll
        for (int j = 0; j < 8; j++) {
            const int k = f * 32 + quad * 8 + j;
            WU.u[f * 8 + j] = __builtin_bit_cast(uint, pk(LAM * W1[k], LAM * W1[HID + k]));
            BU.f[f * 8 + j] = LAM * b1[k];
        }
#pragma unroll
    for (int i = 0; i < 4; i++) {
        ws[i * 64 + lane] = WU.q[i];
        ws[(4 + i) * 64 + lane] = BU.q[i];
    }
#pragma unroll
    for (int t = 0; t < 4; t++)
#pragma unroll
        for (int f = 0; f < 2; f++) {
            union { uint4 q; uint u[4]; } T;
#pragma unroll
            for (int jj = 0; jj < 4; jj++) {
                const int k0 = f * 32 + quad * 8 + 2 * jj;
                const int n  = t * 16 + l15;
                T.u[jj] = __builtin_bit_cast(uint,
                    pk(LAM * W2[k0 * HID + n], LAM * W2[(k0 + 1) * HID + n]));
            }
            ws[(8 + 2 * t + f) * 64 + lane] = T.q;
        }
}

// ---- setup kernel 2: u1 = weight1 * u ----
__global__ __launch_bounds__(256, 8) void premul_u(
    const float* __restrict__ u, const float* __restrict__ w1,
    float* __restrict__ u1)
{
    const int i = blockIdx.x * 256 + threadIdx.x;
    if (i < NDOF / 4) {
        const float4 a = ((const float4*)u)[i];
        const float4 b = ((const float4*)w1)[i];
        ((float4*)u1)[i] = make_float4(a.x * b.x, a.y * b.y, a.z * b.z, a.w * b.w);
    }
}

// one layer-2/3 tile step: C=b2 -> 2 MFMA -> tanh -> packed layer-3 partials
#define TSTEP(tt, qa, qb) do { \
    const float4v b2v = *(const float4v*)&b2t[wv][wb + (tt) * 4]; \
    union { uint4 q; uint u[4]; } w3u; \
    w3u.q = *(const uint4*)&w3t[wv][wb + (tt) * 4]; \
    float4v c = b2v; \
    c = __builtin_amdgcn_mfma_f32_16x16x32_f16(__builtin_bit_cast(half8v, (qa)), B0.v, c, 0, 0, 0); \
    c = __builtin_amdgcn_mfma_f32_16x16x32_f16(__builtin_bit_cast(half8v, (qb)), B1.v, c, 0, 0, 0); \
    _Pragma("unroll") \
    for (int reg = 0; reg < 4; reg++) { \
        const float h = tanh2(c[reg]); \
        const half2v hh = pk(h, h); \
        sp = sp + hh * __builtin_bit_cast(half2v, w3u.u[reg]); \
    } \
} while (0)

// stage one 6KB B-tile (64 rows x 96B) into this wave's LDS buffer via
// global_load_lds, granule-COLUMN-major (s = j*64 + r) so per-row b128
// reads are bank-conflict-free (linear row-major would be 16-way).
#define STAGE(bu, Tt) do { \
    const float* gb_ = B + (size_t)(Tt) * 1536 + lane * 24; \
    _Pragma("unroll") \
    for (int i_ = 0; i_ < 6; i_++) { \
        __builtin_amdgcn_global_load_lds( \
            (const __attribute__((address_space(1))) uint*)(gb_ + i_ * 4), \
            (__attribute__((address_space(3))) uint*)&lbuf[wv][bu][i_ * 256], \
            16, 0, 0); \
    } \
} while (0)

// Barrier-free persistent-wave pipeline. Each wave owns ~10 tiles of
// 64 GP-rows (16 elements); NOTHING is cross-wave (MFMA, swizzles,
// sX/sG/sB all wave-local) so there are ZERO __syncthreads. Per tile:
// stage next tile's B (global_load_lds, dbuf) + prefetch next conn/u/Jacc,
// compute phases 1-3 of current tile. One vmcnt(0) per tile at phase-2
// end, where all outstanding VMEM is >=1.5K cycles old (free drain, no
// counted-vmcnt fragility). lgkmcnt(0)+sched_barrier for within-wave
// cross-lane LDS visibility (rule 18).
__global__ __launch_bounds__(256, 4) void fem_force_kernel(
    const float* __restrict__ u, const float* __restrict__ B,
    const float* __restrict__ Jacc, const float* __restrict__ gp_w,
    const int* __restrict__ conn, const float* __restrict__ weight1,
    const float* __restrict__ scales_inp, const float* __restrict__ limits_inp,
    const float* __restrict__ scales_grad, const float* __restrict__ limits_grad,
    const float* __restrict__ b2, const float* __restrict__ W3,
    const float* __restrict__ b3, const uint4* __restrict__ wt,
    const int premul, float* __restrict__ F)
{
    __shared__ float lbuf[4][2][1536];   // per-wave B dbuf (+sB overlay)
    __shared__ uint  sXs[4][64];         // per-wave packed (x0,x1)
    __shared__ uint  sGs[4][64];         // per-wave packed (p,q)
    __shared__ float b2t[4][64];
    __shared__ uint  w3t[4][64];         // pk(W3[2n], W3[2n+1])

    const int tid  = threadIdx.x;
    const int lane = tid & 63;
    const int wv   = tid >> 6;
    const int quad = lane >> 4;
    const int l15  = lane & 15;
    const int g    = lane & 3;           // gauss point of this thread

    // per-wave b2/W3 tables (no cross-wave writes -> no barrier needed)
    {
        const int i  = lane;
        const int it = (i >> 2) & 3, iq = i >> 4, ir = i & 3;
        const int n  = it * 16 + iq * 4 + ir;
        b2t[wv][i] = LAM * b2[n];
        w3t[wv][i] = __builtin_bit_cast(uint, pk(W3[2 * n], W3[2 * n + 1]));
    }

    const float SQ23 = 0.816496580927726f;
    const float si0 = scales_inp[0], si1 = scales_inp[1];
    const float li0 = limits_inp[0], li1 = limits_inp[1];
    const float isg0 = 1.0f / scales_grad[0], isg1 = 1.0f / scales_grad[1];
    const float b30c = b3[0] - limits_grad[0];
    const float b31c = b3[1] - limits_grad[1];
    const float gw  = gp_w[g];

    // ---- held weight fragments: loaded ONCE per kernel, pinned ----
    union { uint4 q[4]; uint u[16]; } W1U;
    union { uint4 q[4]; float f[16]; } B1U;
    uint4 bfq[8];
#pragma unroll
    for (int i = 0; i < 4; i++) {
        W1U.q[i] = wt[i * 64 + lane];
        B1U.q[i] = wt[(4 + i) * 64 + lane];
    }
#pragma unroll
    for (int i = 0; i < 8; i++) bfq[i] = wt[(8 + i) * 64 + lane];
#pragma unroll
    for (int i = 0; i < 4; i++) {
        asm volatile("" : "+v"(W1U.q[i].x), "+v"(W1U.q[i].y), "+v"(W1U.q[i].z), "+v"(W1U.q[i].w));
        asm volatile("" : "+v"(B1U.q[i].x), "+v"(B1U.q[i].y), "+v"(B1U.q[i].z), "+v"(B1U.q[i].w));
    }
#pragma unroll
    for (int i = 0; i < 8; i++)
        asm volatile("" : "+v"(bfq[i].x), "+v"(bfq[i].y), "+v"(bfq[i].z), "+v"(bfq[i].w));

    // ---- prologue: stage tile 0, prefetch its conn/u/Jacc ----
    int T = blockIdx.x * 4 + wv;         // first tile of this wave
    int cur = 0;
    STAGE(0, T);
    int connT = conn[T * 64 + lane];     // = conn[4e+g] (coalesced)
    asm volatile("s_waitcnt vmcnt(0)");
    __builtin_amdgcn_sched_barrier(0);
    float2 uT = *(const float2*)(u + 2 * connT);
    float  jacT = Jacc[T * 64 + lane];
    float2 wvT = make_float2(1.f, 1.f);
    if (!premul) wvT = *(const float2*)(weight1 + 2 * connT);

    int   connN = 0;
    float2 uN = make_float2(0.f, 0.f), wvN = make_float2(1.f, 1.f);
    float jacN = 0.f;

#pragma unroll 1
    for (; T < NT; T += NWAVE) {
        const int Tn = T + NWAVE;
        const bool hasN = (Tn < NT);
        // stage next tile's B + prefetch next conn (latency hidden under
        // this tile's full compute)
        if (hasN) {
            STAGE(cur ^ 1, Tn);
            connN = conn[Tn * 64 + lane];
        }

        // ---- phase 1: strain invariants -> P,Q overlay + x ----
        {
            const float vx = wvT.x * uT.x, vy = wvT.y * uT.y;
            float ue[8];
            ue[0] = SWZF(vx, 0x1C); ue[1] = SWZF(vy, 0x1C);
            ue[2] = SWZF(vx, 0x3C); ue[3] = SWZF(vy, 0x3C);
            ue[4] = SWZF(vx, 0x5C); ue[5] = SWZF(vy, 0x5C);
            ue[6] = SWZF(vx, 0x7C); ue[7] = SWZF(vy, 0x7C);

            float Bg[24];
#pragma unroll
            for (int j = 0; j < 6; j++) {
                const float4 v = *(const float4*)&lbuf[wv][cur][(j * 64 + lane) * 4];
                Bg[4 * j + 0] = v.x; Bg[4 * j + 1] = v.y;
                Bg[4 * j + 2] = v.z; Bg[4 * j + 3] = v.w;
            }
            float s0 = 0.f, s1 = 0.f, s2 = 0.f;
#pragma unroll
            for (int j = 0; j < 8; j++) {
                s0 = fmaf(Bg[j],      ue[j], s0);
                s1 = fmaf(Bg[8 + j],  ue[j], s1);
                s2 = fmaf(Bg[16 + j], ue[j], s2);
            }
            const float ev  = s0 + s1;
            const float ev3 = ev * (1.0f / 3.0f);
            const float d00 = s0 - ev3, d11 = s1 - ev3, d22 = -ev3, d01 = 0.5f * s2;
            const float det = sqrtf(d00 * d00 + d11 * d11 + d22 * d22 + 2.0f * d01 * d01);
            const float rd  = __builtin_amdgcn_rcpf(det);
            const float es  = det * SQ23;
            const float wgt = jacT * gw;
            const float sc  = SQ23 * rd * wgt;
            const float c00 = sc * d00, c11 = sc * d11, c01 = sc * d01;
            // overlay packed (P[j],Q[j]) into this row's consumed granules 0,1
            union { uint4 q; uint w[4]; } q0, q1;
#pragma unroll
            for (int j = 0; j < 8; j++) {
                const float P = wgt * (Bg[j] + Bg[8 + j]);
                const float Q = fmaf(c00, Bg[j], fmaf(c11, Bg[8 + j], c01 * Bg[16 + j]));
                const uint pq = __builtin_bit_cast(uint, pk(P, Q));
                if (j < 4) q0.w[j] = pq; else q1.w[j - 4] = pq;
            }
            *(uint4*)&lbuf[wv][cur][(0 * 64 + lane) * 4] = q0.q;
            *(uint4*)&lbuf[wv][cur][(1 * 64 + lane) * 4] = q1.q;
            sXs[wv][lane] = __builtin_bit_cast(uint,
                pk(fmaf(ev, si0, li0), fmaf(es, si1, li1)));
        }
        asm volatile("s_waitcnt lgkmcnt(0)");
        __builtin_amdgcn_sched_barrier(0);

        // prefetch next tile's u/weight1/Jacc (conn arrived during phase 1)
        if (hasN) {
            uN = *(const float2*)(u + 2 * connN);
            jacN = Jacc[Tn * 64 + lane];
            if (!premul) wvN = *(const float2*)(weight1 + 2 * connN);
        }

        // ---- phase 2: wave-level MFMA MLP over this wave's 64 rows ----
        int zr = 0;                  // opaque zero: keeps table reads in-loop
#pragma unroll 1
        for (int rt = 0; rt < 4; rt++) {
            asm volatile("" : "+v"(zr));
            const int wb = quad * 16 + zr;
            const half2v xp = __builtin_bit_cast(half2v, sXs[wv][rt * 16 + l15]);

            union { half8v v; uint uu[4]; } B0, B1;
#pragma unroll
            for (int jj = 0; jj < 4; jj++) {
                const float t0 = tanh2(fdot2(xp, __builtin_bit_cast(half2v, W1U.u[2 * jj]),     B1U.f[2 * jj]));
                const float t1 = tanh2(fdot2(xp, __builtin_bit_cast(half2v, W1U.u[2 * jj + 1]), B1U.f[2 * jj + 1]));
                const float t2 = tanh2(fdot2(xp, __builtin_bit_cast(half2v, W1U.u[8 + 2 * jj]),     B1U.f[8 + 2 * jj]));
                const float t3 = tanh2(fdot2(xp, __builtin_bit_cast(half2v, W1U.u[8 + 2 * jj + 1]), B1U.f[8 + 2 * jj + 1]));
                B0.uu[jj] = __builtin_bit_cast(uint, pk(t0, t1));
                B1.uu[jj] = __builtin_bit_cast(uint, pk(t2, t3));
            }

            half2v sp = {_Float16(0.f), _Float16(0.f)};
            TSTEP(0, bfq[0], bfq[1]);
            TSTEP(1, bfq[2], bfq[3]);
            TSTEP(2, bfq[4], bfq[5]);
            TSTEP(3, bfq[6], bfq[7]);

            float s0 = (float)sp[0], s1 = (float)sp[1];
            s0 += SWZF(s0, 0x401F);
            s1 += SWZF(s1, 0x401F);
            s0 += __shfl_xor(s0, 32, 64);
            s1 += __shfl_xor(s1, 32, 64);
            if (quad == 0) {
                const float p = (s0 + b30c) * isg0;
                const float q = (s1 + b31c) * isg1;
                sGs[wv][rt * 16 + l15] = __builtin_bit_cast(uint, pk(p, q));
            }
        }
        // one wait per tile: everything outstanding (next-tile glds,
        // uN/jacN/connN, previous tile's atomics) is >=1.5K cycles old.
        asm volatile("s_waitcnt vmcnt(0) lgkmcnt(0)");
        __builtin_amdgcn_sched_barrier(0);

        // ---- phase 3: EP pair via fdot2 of (p,q)x(P,Q), 2 atomics ----
        {
            const int rb = lane & ~3;
            const int k0 = 2 * g;
            const uint* lb = (const uint*)&lbuf[wv][cur][0];
            float a = 0.f, b = 0.f;
#pragma unroll
            for (int gp = 0; gp < 4; gp++) {
                const int rr = rb + gp;
                const half2v pq = __builtin_bit_cast(half2v, sGs[wv][rr]);
                const uint2 w01 = *(const uint2*)&lb[((k0 >> 2) * 64 + rr) * 4 + (k0 & 3)];
                a = fdot2(pq, __builtin_bit_cast(half2v, w01.x), a);
                b = fdot2(pq, __builtin_bit_cast(half2v, w01.y), b);
            }
            atomicAdd(&F[2 * connT],     a);
            atomicAdd(&F[2 * connT + 1], b);
        }

        cur ^= 1;
        connT = connN; uT = uN; jacT = jacN; wvT = wvN;
    }
}

extern "C" void kernel_launch(void* const* d_in, const int* in_sizes, int n_in,
                              void* d_out, int out_size, void* d_ws, size_t ws_size,
                              hipStream_t stream) {
    const float* u           = (const float*)d_in[0];
    const float* B           = (const float*)d_in[1];
    const float* Jacc        = (const float*)d_in[2];
    const float* gp_w        = (const float*)d_in[3];
    const int*   conn        = (const int*)  d_in[4];
    const float* weight1     = (const float*)d_in[5];
    const float* scales_inp  = (const float*)d_in[6];
    const float* limits_inp  = (const float*)d_in[7];
    const float* scales_grad = (const float*)d_in[8];
    const float* limits_grad = (const float*)d_in[9];
    const float* W1          = (const float*)d_in[10];
    const float* b1          = (const float*)d_in[11];
    const float* W2          = (const float*)d_in[12];
    const float* b2          = (const float*)d_in[13];
    const float* W3          = (const float*)d_in[14];
    const float* b3          = (const float*)d_in[15];
    float* F = (float*)d_out;

    uint4* wt = (uint4*)d_ws;                       // 16 KB weight table
    float* u1 = (float*)((char*)d_ws + 16384);      // 2 MB premultiplied u
    const int can_premul = (ws_size >= 16384 + sizeof(float) * NDOF) ? 1 : 0;

    (void)hipMemsetAsync(d_out, 0, sizeof(float) * NDOF, stream);

    pack_weights<<<1, 64, 0, stream>>>(W1, b1, W2, wt);
    if (can_premul)
        premul_u<<<(NDOF / 4 + 255) / 256, 256, 0, stream>>>(u, weight1, u1);

    fem_force_kernel<<<NBLK, 256, 0, stream>>>(
        can_premul ? u1 : u, B, Jacc, gp_w, conn, weight1,
        scales_inp, limits_inp, scales_grad, limits_grad,
        b2, W3, b3, wt, can_premul, F);
}

// Round 7
// 450.187 us; speedup vs baseline: 1.0077x; 1.0077x over previous
//
#include <hip/hip_runtime.h>

#define NELEM 500000
#define NDOF 500000
#define HID 64
#define NT 31250                 // wave-tiles: 2M GP-rows / 64 (exact)
#define NBLK 1024                // 4 blocks/CU * 256 CU
#define NWAVE (NBLK * 4)

typedef _Float16 half2v __attribute__((ext_vector_type(2)));
typedef _Float16 half8v __attribute__((ext_vector_type(8)));
typedef float float4v __attribute__((ext_vector_type(4)));

// lambda = 2*log2(e): prescaled into W1,b1,W2,b2 so tanh needs no multiply.
#define LAM 2.885390081777927f

__device__ __forceinline__ half2v pk(float a, float b) {
    return __builtin_bit_cast(half2v, __builtin_amdgcn_cvt_pkrtz(a, b));
}
// tanh(z) with y = LAM*z prescaled. exp2(+-inf) saturates correctly.
__device__ __forceinline__ float tanh2(float y) {
    float e = __builtin_amdgcn_exp2f(y);
    float r = __builtin_amdgcn_rcpf(e + 1.0f);
    return fmaf(-2.0f, r, 1.0f);
}
__device__ __forceinline__ float fdot2(half2v a, half2v b, float c) {
    return __builtin_amdgcn_fdot2(a, b, c, false);
}

// ds_swizzle BitMode: src = ((lane&AND)|OR)^XOR within 32-lane halves.
//   quad broadcast j: 0x1C,0x3C,0x5C,0x7C ; xor16: 0x401F
#define SWZF(x, pat) __builtin_bit_cast(float, \
    __builtin_amdgcn_ds_swizzle(__builtin_bit_cast(int, (x)), (pat)))

// ---- setup kernel 1: pack per-lane W2 MFMA fragments into workspace ----
// wt[8+2t+f][lane]: half8 W2 fragments (A-operand of swapped MFMA).
__global__ __launch_bounds__(64, 1) void pack_weights(
    const float* __restrict__ W2, uint4* __restrict__ ws)
{
    const int lane = threadIdx.x & 63;
    const int quad = lane >> 4, l15 = lane & 15;
#pragma unroll
    for (int t = 0; t < 4; t++)
#pragma unroll
        for (int f = 0; f < 2; f++) {
            union { uint4 q; uint u[4]; } T;
#pragma unroll
            for (int jj = 0; jj < 4; jj++) {
                const int k0 = f * 32 + quad * 8 + 2 * jj;
                const int n  = t * 16 + l15;
                T.u[jj] = __builtin_bit_cast(uint,
                    pk(LAM * W2[k0 * HID + n], LAM * W2[(k0 + 1) * HID + n]));
            }
            ws[(8 + 2 * t + f) * 64 + lane] = T.q;
        }
}

// ---- setup kernel 2: u1 = weight1 * u ----
__global__ __launch_bounds__(256, 8) void premul_u(
    const float* __restrict__ u, const float* __restrict__ w1,
    float* __restrict__ u1)
{
    const int i = blockIdx.x * 256 + threadIdx.x;
    if (i < NDOF / 4) {
        const float4 a = ((const float4*)u)[i];
        const float4 b = ((const float4*)w1)[i];
        ((float4*)u1)[i] = make_float4(a.x * b.x, a.y * b.y, a.z * b.z, a.w * b.w);
    }
}

// one layer-2/3 tile step: C=b2 -> 2 MFMA -> tanh -> packed layer-3 partials
#define TSTEP(tt, qa, qb) do { \
    const float4v b2v = *(const float4v*)&b2t[wb + (tt) * 4]; \
    union { uint4 q; uint u[4]; } w3u; \
    w3u.q = *(const uint4*)&w3t[wb + (tt) * 4]; \
    float4v c = b2v; \
    c = __builtin_amdgcn_mfma_f32_16x16x32_f16(__builtin_bit_cast(half8v, (qa)), B0.v, c, 0, 0, 0); \
    c = __builtin_amdgcn_mfma_f32_16x16x32_f16(__builtin_bit_cast(half8v, (qb)), B1.v, c, 0, 0, 0); \
    _Pragma("unroll") \
    for (int reg = 0; reg < 4; reg++) { \
        const float h = tanh2(c[reg]); \
        const half2v hh = pk(h, h); \
        sp = sp + hh * __builtin_bit_cast(half2v, w3u.u[reg]); \
    } \
} while (0)

// Barrier-free persistent-wave pipeline, register-staged B.
// r6's skeleton (prefetch conn a phase early, u mid-tile, one vmcnt(0)
// drain per tile) but B goes straight to 6 float4 registers instead of a
// 48KB LDS dbuf: LDS drops to ~12KB -> 4 blocks/CU -> 16 waves/CU (2x r6).
// To pay for the 24 B-regs, layer-1 W1/b1 move to 512B quad-broadcast LDS
// tables read per-rt behind the zr guard (same-addr within quad = free).
// P,Q overlay lives in plane-padded LDS (j*260+wv*65+row): all reads and
// writes <=2-way bank aliasing (free per m136).
__global__ __launch_bounds__(256, 4) void fem_force_kernel(
    const float* __restrict__ u, const float* __restrict__ B,
    const float* __restrict__ Jacc, const float* __restrict__ gp_w,
    const int* __restrict__ conn, const float* __restrict__ weight1,
    const float* __restrict__ scales_inp, const float* __restrict__ limits_inp,
    const float* __restrict__ scales_grad, const float* __restrict__ limits_grad,
    const float* __restrict__ W1, const float* __restrict__ b1,
    const float* __restrict__ b2, const float* __restrict__ W3,
    const float* __restrict__ b3, const uint4* __restrict__ wt,
    const int premul, float* __restrict__ F)
{
    __shared__ uint sPQ[8 * 260];        // plane j at j*260 + wv*65 + row
    __shared__ uint sXs[4][64];          // per-wave packed (x0,x1)
    __shared__ uint sGs[4][64];          // per-wave packed (p,q)
    __shared__ __align__(16) float b2t[64];
    __shared__ __align__(16) uint  w3t[64];      // pk(W3[2n], W3[2n+1])
    __shared__ __align__(16) uint  w1tb[4][16];  // per-quad LAM*W1 pairs
    __shared__ __align__(16) float b1tb[4][16];  // per-quad LAM*b1

    const int tid  = threadIdx.x;
    const int lane = tid & 63;
    const int wv   = tid >> 6;
    const int quad = lane >> 4;
    const int l15  = lane & 15;
    const int g    = lane & 3;           // gauss point of this thread
    const int pqb  = wv * 65;            // this wave's sPQ row base

    // block-shared tables (one copy), single barrier before the loop
    if (tid < 64) {
        const int i  = tid;
        const int it = (i >> 2) & 3, iq = i >> 4, ir = i & 3;
        const int n  = it * 16 + iq * 4 + ir;
        b2t[i] = LAM * b2[n];
        w3t[i] = __builtin_bit_cast(uint, pk(W3[2 * n], W3[2 * n + 1]));
    } else if (tid < 128) {
        const int i = tid - 64;          // i = q*16 + idx
        const int q = i >> 4, idx = i & 15, f = idx >> 3, jj = idx & 7;
        const int k = f * 32 + q * 8 + jj;
        w1tb[q][idx] = __builtin_bit_cast(uint, pk(LAM * W1[k], LAM * W1[HID + k]));
    } else if (tid < 192) {
        const int i = tid - 128;
        const int q = i >> 4, idx = i & 15, f = idx >> 3, jj = idx & 7;
        const int k = f * 32 + q * 8 + jj;
        b1tb[q][idx] = LAM * b1[k];
    }
    __syncthreads();

    const float SQ23 = 0.816496580927726f;
    const float si0 = scales_inp[0], si1 = scales_inp[1];
    const float li0 = limits_inp[0], li1 = limits_inp[1];
    const float isg0 = 1.0f / scales_grad[0], isg1 = 1.0f / scales_grad[1];
    const float b30c = b3[0] - limits_grad[0];
    const float b31c = b3[1] - limits_grad[1];
    const float gw  = gp_w[g];

    // ---- held W2 fragments: loaded ONCE, pinned (r5-proven) ----
    uint4 bfq[8];
#pragma unroll
    for (int i = 0; i < 8; i++) bfq[i] = wt[(8 + i) * 64 + lane];
#pragma unroll
    for (int i = 0; i < 8; i++)
        asm volatile("" : "+v"(bfq[i].x), "+v"(bfq[i].y), "+v"(bfq[i].z), "+v"(bfq[i].w));

    // ---- prologue: B + conn + u/Jacc for tile 0 ----
    int T = blockIdx.x * 4 + wv;
    float4 bq0, bq1, bq2, bq3, bq4, bq5;
    {
        const float4* Bp = (const float4*)(B + (size_t)T * 1536 + lane * 24);
        bq0 = Bp[0]; bq1 = Bp[1]; bq2 = Bp[2];
        bq3 = Bp[3]; bq4 = Bp[4]; bq5 = Bp[5];
    }
    int connT = conn[T * 64 + lane];
    float jacT = Jacc[T * 64 + lane];
    float2 uT = *(const float2*)(u + 2 * connT);
    float2 wvT = make_float2(1.f, 1.f);
    if (!premul) wvT = *(const float2*)(weight1 + 2 * connT);

    int connN = 0;
    float2 uN = make_float2(0.f, 0.f), wvN = make_float2(1.f, 1.f);
    float jacN = 0.f;

#pragma unroll 1
    for (; T < NT; T += NWAVE) {
        const int Tn = T + NWAVE;
        const bool hasN = (Tn < NT);
        // prefetch next conn/Jacc (independent loads; land during phase 1)
        if (hasN) {
            connN = conn[Tn * 64 + lane];
            jacN  = Jacc[Tn * 64 + lane];
        }

        // ---- phase 1: strain invariants -> P,Q planes + x ----
        {
            const float vx = wvT.x * uT.x, vy = wvT.y * uT.y;
            float ue[8];
            ue[0] = SWZF(vx, 0x1C); ue[1] = SWZF(vy, 0x1C);
            ue[2] = SWZF(vx, 0x3C); ue[3] = SWZF(vy, 0x3C);
            ue[4] = SWZF(vx, 0x5C); ue[5] = SWZF(vy, 0x5C);
            ue[6] = SWZF(vx, 0x7C); ue[7] = SWZF(vy, 0x7C);

            float Bg[24];
            Bg[0]=bq0.x; Bg[1]=bq0.y; Bg[2]=bq0.z; Bg[3]=bq0.w;
            Bg[4]=bq1.x; Bg[5]=bq1.y; Bg[6]=bq1.z; Bg[7]=bq1.w;
            Bg[8]=bq2.x; Bg[9]=bq2.y; Bg[10]=bq2.z; Bg[11]=bq2.w;
            Bg[12]=bq3.x; Bg[13]=bq3.y; Bg[14]=bq3.z; Bg[15]=bq3.w;
            Bg[16]=bq4.x; Bg[17]=bq4.y; Bg[18]=bq4.z; Bg[19]=bq4.w;
            Bg[20]=bq5.x; Bg[21]=bq5.y; Bg[22]=bq5.z; Bg[23]=bq5.w;

            float s0 = 0.f, s1 = 0.f, s2 = 0.f;
#pragma unroll
            for (int j = 0; j < 8; j++) {
                s0 = fmaf(Bg[j],      ue[j], s0);
                s1 = fmaf(Bg[8 + j],  ue[j], s1);
                s2 = fmaf(Bg[16 + j], ue[j], s2);
            }
            const float ev  = s0 + s1;
            const float ev3 = ev * (1.0f / 3.0f);
            const float d00 = s0 - ev3, d11 = s1 - ev3, d22 = -ev3, d01 = 0.5f * s2;
            const float det = sqrtf(d00 * d00 + d11 * d11 + d22 * d22 + 2.0f * d01 * d01);
            const float rd  = __builtin_amdgcn_rcpf(det);
            const float es  = det * SQ23;
            const float wgt = jacT * gw;
            const float sc  = SQ23 * rd * wgt;
            const float c00 = sc * d00, c11 = sc * d11, c01 = sc * d01;
#pragma unroll
            for (int j = 0; j < 8; j++) {
                const float P = wgt * (Bg[j] + Bg[8 + j]);
                const float Q = fmaf(c00, Bg[j], fmaf(c11, Bg[8 + j], c01 * Bg[16 + j]));
                sPQ[j * 260 + pqb + lane] = __builtin_bit_cast(uint, pk(P, Q));
            }
            sXs[wv][lane] = __builtin_bit_cast(uint,
                pk(fmaf(ev, si0, li0), fmaf(es, si1, li1)));
        }
        // reload B regs for next tile (consumed above; land during phase 2)
        if (hasN) {
            const float4* Bp = (const float4*)(B + (size_t)Tn * 1536 + lane * 24);
            bq0 = Bp[0]; bq1 = Bp[1]; bq2 = Bp[2];
            bq3 = Bp[3]; bq4 = Bp[4]; bq5 = Bp[5];
        }
        asm volatile("s_waitcnt lgkmcnt(0)");
        __builtin_amdgcn_sched_barrier(0);
        // prefetch next u/weight1 (connN landed during phase 1)
        if (hasN) {
            uN = *(const float2*)(u + 2 * connN);
            if (!premul) wvN = *(const float2*)(weight1 + 2 * connN);
        }

        // ---- phase 2: wave-level MFMA MLP over this wave's 64 rows ----
        int zr = 0;                  // opaque zero: keeps table reads in-loop
#pragma unroll 1
        for (int rt = 0; rt < 4; rt++) {
            asm volatile("" : "+v"(zr));
            const int qz = quad + zr;
            const int wb = qz * 16;
            const half2v xp = __builtin_bit_cast(half2v, sXs[wv][rt * 16 + l15]);

            // layer-1 weights: quad-broadcast LDS reads (conflict-free)
            union { uint4 q[4]; uint u[16]; } W1L;
            union { float4 q[4]; float f[16]; } B1L;
#pragma unroll
            for (int i = 0; i < 4; i++) {
                W1L.q[i] = *(const uint4*)&w1tb[qz][4 * i];
                B1L.q[i] = *(const float4*)&b1tb[qz][4 * i];
            }

            union { half8v v; uint uu[4]; } B0, B1;
#pragma unroll
            for (int jj = 0; jj < 4; jj++) {
                const float t0 = tanh2(fdot2(xp, __builtin_bit_cast(half2v, W1L.u[2 * jj]),     B1L.f[2 * jj]));
                const float t1 = tanh2(fdot2(xp, __builtin_bit_cast(half2v, W1L.u[2 * jj + 1]), B1L.f[2 * jj + 1]));
                const float t2 = tanh2(fdot2(xp, __builtin_bit_cast(half2v, W1L.u[8 + 2 * jj]),     B1L.f[8 + 2 * jj]));
                const float t3 = tanh2(fdot2(xp, __builtin_bit_cast(half2v, W1L.u[8 + 2 * jj + 1]), B1L.f[8 + 2 * jj + 1]));
                B0.uu[jj] = __builtin_bit_cast(uint, pk(t0, t1));
                B1.uu[jj] = __builtin_bit_cast(uint, pk(t2, t3));
            }

            half2v sp = {_Float16(0.f), _Float16(0.f)};
            TSTEP(0, bfq[0], bfq[1]);
            TSTEP(1, bfq[2], bfq[3]);
            TSTEP(2, bfq[4], bfq[5]);
            TSTEP(3, bfq[6], bfq[7]);

            float s0 = (float)sp[0], s1 = (float)sp[1];
            s0 += SWZF(s0, 0x401F);
            s1 += SWZF(s1, 0x401F);
            s0 += __shfl_xor(s0, 32, 64);
            s1 += __shfl_xor(s1, 32, 64);
            if (quad == 0) {
                const float p = (s0 + b30c) * isg0;
                const float q = (s1 + b31c) * isg1;
                sGs[wv][rt * 16 + l15] = __builtin_bit_cast(uint, pk(p, q));
            }
        }
        // one drain per tile: B regs, uN and the PREVIOUS tile's atomics
        // are all >= one phase old here.
        asm volatile("s_waitcnt vmcnt(0) lgkmcnt(0)");
        __builtin_amdgcn_sched_barrier(0);

        // ---- phase 3: EP pair via fdot2 of (p,q)x(P,Q), 2 atomics ----
        {
            const int rb = lane & ~3;
            const int j0 = 2 * g;
            float a = 0.f, b = 0.f;
#pragma unroll
            for (int gp = 0; gp < 4; gp++) {
                const int rr = rb + gp;
                const half2v pq = __builtin_bit_cast(half2v, sGs[wv][rr]);
                const uint w0 = sPQ[j0 * 260 + pqb + rr];
                const uint w1 = sPQ[(j0 + 1) * 260 + pqb + rr];
                a = fdot2(pq, __builtin_bit_cast(half2v, w0), a);
                b = fdot2(pq, __builtin_bit_cast(half2v, w1), b);
            }
            atomicAdd(&F[2 * connT],     a);
            atomicAdd(&F[2 * connT + 1], b);
        }

        connT = connN; uT = uN; jacT = jacN; wvT = wvN;
    }
}

extern "C" void kernel_launch(void* const* d_in, const int* in_sizes, int n_in,
                              void* d_out, int out_size, void* d_ws, size_t ws_size,
                              hipStream_t stream) {
    const float* u           = (const float*)d_in[0];
    const float* B           = (const float*)d_in[1];
    const float* Jacc        = (const float*)d_in[2];
    const float* gp_w        = (const float*)d_in[3];
    const int*   conn        = (const int*)  d_in[4];
    const float* weight1     = (const float*)d_in[5];
    const float* scales_inp  = (const float*)d_in[6];
    const float* limits_inp  = (const float*)d_in[7];
    const float* scales_grad = (const float*)d_in[8];
    const float* limits_grad = (const float*)d_in[9];
    const float* W1          = (const float*)d_in[10];
    const float* b1          = (const float*)d_in[11];
    const float* W2          = (const float*)d_in[12];
    const float* b2          = (const float*)d_in[13];
    const float* W3          = (const float*)d_in[14];
    const float* b3          = (const float*)d_in[15];
    float* F = (float*)d_out;

    uint4* wt = (uint4*)d_ws;                       // 16 KB weight table
    float* u1 = (float*)((char*)d_ws + 16384);      // 2 MB premultiplied u
    const int can_premul = (ws_size >= 16384 + sizeof(float) * NDOF) ? 1 : 0;

    (void)hipMemsetAsync(d_out, 0, sizeof(float) * NDOF, stream);

    pack_weights<<<1, 64, 0, stream>>>(W2, wt);
    if (can_premul)
        premul_u<<<(NDOF / 4 + 255) / 256, 256, 0, stream>>>(u, weight1, u1);

    fem_force_kernel<<<NBLK, 256, 0, stream>>>(
        can_premul ? u1 : u, B, Jacc, gp_w, conn, weight1,
        scales_inp, limits_inp, scales_grad, limits_grad,
        W1, b1, b2, W3, b3, wt, can_premul, F);
}

// Round 8
// 354.578 us; speedup vs baseline: 1.2794x; 1.2696x over previous
//
#include <hip/hip_runtime.h>

#define NELEM 500000
#define NDOF 500000
#define NNODE 250000
#define HID 64
#define NT 31250                 // wave-tiles: 2M GP-rows / 64 (exact)
#define NBLK 1024                // 4 blocks/CU * 256 CU
#define NWAVE (NBLK * 4)

typedef _Float16 half2v __attribute__((ext_vector_type(2)));
typedef _Float16 half8v __attribute__((ext_vector_type(8)));
typedef float float4v __attribute__((ext_vector_type(4)));

// lambda = 2*log2(e): prescaled into W1,b1,W2,b2 so tanh needs no multiply.
#define LAM 2.885390081777927f
// fixed-point scale for the u64 packed atomic accumulate (range +-512,
// resolution 2.4e-7; lo->hi carry pollution <= 16*2^-22 ~ 4e-6 << 0.0625)
#define FSCALE 4194304.0f        // 2^22
#define FINV   2.384185791015625e-7f

__device__ __forceinline__ half2v pk(float a, float b) {
    return __builtin_bit_cast(half2v, __builtin_amdgcn_cvt_pkrtz(a, b));
}
// tanh(z) with y = LAM*z prescaled. exp2(+-inf) saturates correctly.
__device__ __forceinline__ float tanh2(float y) {
    float e = __builtin_amdgcn_exp2f(y);
    float r = __builtin_amdgcn_rcpf(e + 1.0f);
    return fmaf(-2.0f, r, 1.0f);
}
__device__ __forceinline__ float fdot2(half2v a, half2v b, float c) {
    return __builtin_amdgcn_fdot2(a, b, c, false);
}

// ds_swizzle BitMode: src = ((lane&AND)|OR)^XOR within 32-lane halves.
//   quad broadcast j: 0x1C,0x3C,0x5C,0x7C ; xor16: 0x401F
#define SWZF(x, pat) __builtin_bit_cast(float, \
    __builtin_amdgcn_ds_swizzle(__builtin_bit_cast(int, (x)), (pat)))

// ---- setup kernel 1: pack per-lane W2 MFMA fragments into workspace ----
__global__ __launch_bounds__(64, 1) void pack_weights(
    const float* __restrict__ W2, uint4* __restrict__ ws)
{
    const int lane = threadIdx.x & 63;
    const int quad = lane >> 4, l15 = lane & 15;
#pragma unroll
    for (int t = 0; t < 4; t++)
#pragma unroll
        for (int f = 0; f < 2; f++) {
            union { uint4 q; uint u[4]; } T;
#pragma unroll
            for (int jj = 0; jj < 4; jj++) {
                const int k0 = f * 32 + quad * 8 + 2 * jj;
                const int n  = t * 16 + l15;
                T.u[jj] = __builtin_bit_cast(uint,
                    pk(LAM * W2[k0 * HID + n], LAM * W2[(k0 + 1) * HID + n]));
            }
            ws[(8 + 2 * t + f) * 64 + lane] = T.q;
        }
}

// ---- setup kernel 2: u1 = weight1 * u ----
__global__ __launch_bounds__(256, 8) void premul_u(
    const float* __restrict__ u, const float* __restrict__ w1,
    float* __restrict__ u1)
{
    const int i = blockIdx.x * 256 + threadIdx.x;
    if (i < NDOF / 4) {
        const float4 a = ((const float4*)u)[i];
        const float4 b = ((const float4*)w1)[i];
        ((float4*)u1)[i] = make_float4(a.x * b.x, a.y * b.y, a.z * b.z, a.w * b.w);
    }
}

// ---- epilogue: in-place u64 fixed-point -> 2x f32 (one thread per node) ----
__global__ __launch_bounds__(256, 8) void convert_F(unsigned long long* __restrict__ F64)
{
    const int i = blockIdx.x * 256 + threadIdx.x;
    if (i < NNODE) {
        const unsigned long long v = F64[i];
        const int lo = (int)(unsigned)(v & 0xFFFFFFFFull);
        const int hi = (int)(unsigned)(v >> 32);
        float2 out = make_float2((float)lo * FINV, (float)hi * FINV);
        *(float2*)&F64[i] = out;
    }
}

// one layer-2/3 tile step: C=b2 -> 2 MFMA -> tanh -> packed layer-3 partials
#define TSTEP(tt, qa, qb) do { \
    const float4v b2v = *(const float4v*)&b2t[wb + (tt) * 4]; \
    union { uint4 q; uint u[4]; } w3u; \
    w3u.q = *(const uint4*)&w3t[wb + (tt) * 4]; \
    float4v c = b2v; \
    c = __builtin_amdgcn_mfma_f32_16x16x32_f16(__builtin_bit_cast(half8v, (qa)), B0.v, c, 0, 0, 0); \
    c = __builtin_amdgcn_mfma_f32_16x16x32_f16(__builtin_bit_cast(half8v, (qb)), B1.v, c, 0, 0, 0); \
    _Pragma("unroll") \
    for (int reg = 0; reg < 4; reg++) { \
        const float h = tanh2(c[reg]); \
        const half2v hh = pk(h, h); \
        sp = sp + hh * __builtin_bit_cast(half2v, w3u.u[reg]); \
    } \
} while (0)

// Barrier-free persistent-wave pipeline, register-staged B (r7 structure,
// byte-identical except phase 3). Phase 3 now emits ONE u64 fixed-point
// atomicAdd per (element,node) pair instead of two f32 atomicAdds: the
// scatter is atomic-OPERATION-throughput-bound (r5/r6/r7 all pinned at
// ~220us = 4M atomics at ~18G/s regardless of structure), so halving the
// op count is the only lever left.
__global__ __launch_bounds__(256, 4) void fem_force_kernel(
    const float* __restrict__ u, const float* __restrict__ B,
    const float* __restrict__ Jacc, const float* __restrict__ gp_w,
    const int* __restrict__ conn, const float* __restrict__ weight1,
    const float* __restrict__ scales_inp, const float* __restrict__ limits_inp,
    const float* __restrict__ scales_grad, const float* __restrict__ limits_grad,
    const float* __restrict__ W1, const float* __restrict__ b1,
    const float* __restrict__ b2, const float* __restrict__ W3,
    const float* __restrict__ b3, const uint4* __restrict__ wt,
    const int premul, unsigned long long* __restrict__ F64)
{
    __shared__ uint sPQ[8 * 260];        // plane j at j*260 + wv*65 + row
    __shared__ uint sXs[4][64];          // per-wave packed (x0,x1)
    __shared__ uint sGs[4][64];          // per-wave packed (p,q)
    __shared__ __align__(16) float b2t[64];
    __shared__ __align__(16) uint  w3t[64];      // pk(W3[2n], W3[2n+1])
    __shared__ __align__(16) uint  w1tb[4][16];  // per-quad LAM*W1 pairs
    __shared__ __align__(16) float b1tb[4][16];  // per-quad LAM*b1

    const int tid  = threadIdx.x;
    const int lane = tid & 63;
    const int wv   = tid >> 6;
    const int quad = lane >> 4;
    const int l15  = lane & 15;
    const int g    = lane & 3;           // gauss point of this thread
    const int pqb  = wv * 65;            // this wave's sPQ row base

    // block-shared tables (one copy), single barrier before the loop
    if (tid < 64) {
        const int i  = tid;
        const int it = (i >> 2) & 3, iq = i >> 4, ir = i & 3;
        const int n  = it * 16 + iq * 4 + ir;
        b2t[i] = LAM * b2[n];
        w3t[i] = __builtin_bit_cast(uint, pk(W3[2 * n], W3[2 * n + 1]));
    } else if (tid < 128) {
        const int i = tid - 64;          // i = q*16 + idx
        const int q = i >> 4, idx = i & 15, f = idx >> 3, jj = idx & 7;
        const int k = f * 32 + q * 8 + jj;
        w1tb[q][idx] = __builtin_bit_cast(uint, pk(LAM * W1[k], LAM * W1[HID + k]));
    } else if (tid < 192) {
        const int i = tid - 128;
        const int q = i >> 4, idx = i & 15, f = idx >> 3, jj = idx & 7;
        const int k = f * 32 + q * 8 + jj;
        b1tb[q][idx] = LAM * b1[k];
    }
    __syncthreads();

    const float SQ23 = 0.816496580927726f;
    const float si0 = scales_inp[0], si1 = scales_inp[1];
    const float li0 = limits_inp[0], li1 = limits_inp[1];
    const float isg0 = 1.0f / scales_grad[0], isg1 = 1.0f / scales_grad[1];
    const float b30c = b3[0] - limits_grad[0];
    const float b31c = b3[1] - limits_grad[1];
    const float gw  = gp_w[g];

    // ---- held W2 fragments: loaded ONCE, pinned (r5-proven) ----
    uint4 bfq[8];
#pragma unroll
    for (int i = 0; i < 8; i++) bfq[i] = wt[(8 + i) * 64 + lane];
#pragma unroll
    for (int i = 0; i < 8; i++)
        asm volatile("" : "+v"(bfq[i].x), "+v"(bfq[i].y), "+v"(bfq[i].z), "+v"(bfq[i].w));

    // ---- prologue: B + conn + u/Jacc for tile 0 ----
    int T = blockIdx.x * 4 + wv;
    float4 bq0, bq1, bq2, bq3, bq4, bq5;
    {
        const float4* Bp = (const float4*)(B + (size_t)T * 1536 + lane * 24);
        bq0 = Bp[0]; bq1 = Bp[1]; bq2 = Bp[2];
        bq3 = Bp[3]; bq4 = Bp[4]; bq5 = Bp[5];
    }
    int connT = conn[T * 64 + lane];
    float jacT = Jacc[T * 64 + lane];
    float2 uT = *(const float2*)(u + 2 * connT);
    float2 wvT = make_float2(1.f, 1.f);
    if (!premul) wvT = *(const float2*)(weight1 + 2 * connT);

    int connN = 0;
    float2 uN = make_float2(0.f, 0.f), wvN = make_float2(1.f, 1.f);
    float jacN = 0.f;

#pragma unroll 1
    for (; T < NT; T += NWAVE) {
        const int Tn = T + NWAVE;
        const bool hasN = (Tn < NT);
        // prefetch next conn/Jacc (independent loads; land during phase 1)
        if (hasN) {
            connN = conn[Tn * 64 + lane];
            jacN  = Jacc[Tn * 64 + lane];
        }

        // ---- phase 1: strain invariants -> P,Q planes + x ----
        {
            const float vx = wvT.x * uT.x, vy = wvT.y * uT.y;
            float ue[8];
            ue[0] = SWZF(vx, 0x1C); ue[1] = SWZF(vy, 0x1C);
            ue[2] = SWZF(vx, 0x3C); ue[3] = SWZF(vy, 0x3C);
            ue[4] = SWZF(vx, 0x5C); ue[5] = SWZF(vy, 0x5C);
            ue[6] = SWZF(vx, 0x7C); ue[7] = SWZF(vy, 0x7C);

            float Bg[24];
            Bg[0]=bq0.x; Bg[1]=bq0.y; Bg[2]=bq0.z; Bg[3]=bq0.w;
            Bg[4]=bq1.x; Bg[5]=bq1.y; Bg[6]=bq1.z; Bg[7]=bq1.w;
            Bg[8]=bq2.x; Bg[9]=bq2.y; Bg[10]=bq2.z; Bg[11]=bq2.w;
            Bg[12]=bq3.x; Bg[13]=bq3.y; Bg[14]=bq3.z; Bg[15]=bq3.w;
            Bg[16]=bq4.x; Bg[17]=bq4.y; Bg[18]=bq4.z; Bg[19]=bq4.w;
            Bg[20]=bq5.x; Bg[21]=bq5.y; Bg[22]=bq5.z; Bg[23]=bq5.w;

            float s0 = 0.f, s1 = 0.f, s2 = 0.f;
#pragma unroll
            for (int j = 0; j < 8; j++) {
                s0 = fmaf(Bg[j],      ue[j], s0);
                s1 = fmaf(Bg[8 + j],  ue[j], s1);
                s2 = fmaf(Bg[16 + j], ue[j], s2);
            }
            const float ev  = s0 + s1;
            const float ev3 = ev * (1.0f / 3.0f);
            const float d00 = s0 - ev3, d11 = s1 - ev3, d22 = -ev3, d01 = 0.5f * s2;
            const float det = sqrtf(d00 * d00 + d11 * d11 + d22 * d22 + 2.0f * d01 * d01);
            const float rd  = __builtin_amdgcn_rcpf(det);
            const float es  = det * SQ23;
            const float wgt = jacT * gw;
            const float sc  = SQ23 * rd * wgt;
            const float c00 = sc * d00, c11 = sc * d11, c01 = sc * d01;
#pragma unroll
            for (int j = 0; j < 8; j++) {
                const float P = wgt * (Bg[j] + Bg[8 + j]);
                const float Q = fmaf(c00, Bg[j], fmaf(c11, Bg[8 + j], c01 * Bg[16 + j]));
                sPQ[j * 260 + pqb + lane] = __builtin_bit_cast(uint, pk(P, Q));
            }
            sXs[wv][lane] = __builtin_bit_cast(uint,
                pk(fmaf(ev, si0, li0), fmaf(es, si1, li1)));
        }
        // reload B regs for next tile (consumed above; land during phase 2)
        if (hasN) {
            const float4* Bp = (const float4*)(B + (size_t)Tn * 1536 + lane * 24);
            bq0 = Bp[0]; bq1 = Bp[1]; bq2 = Bp[2];
            bq3 = Bp[3]; bq4 = Bp[4]; bq5 = Bp[5];
        }
        asm volatile("s_waitcnt lgkmcnt(0)");
        __builtin_amdgcn_sched_barrier(0);
        // prefetch next u/weight1 (connN landed during phase 1)
        if (hasN) {
            uN = *(const float2*)(u + 2 * connN);
            if (!premul) wvN = *(const float2*)(weight1 + 2 * connN);
        }

        // ---- phase 2: wave-level MFMA MLP over this wave's 64 rows ----
        int zr = 0;                  // opaque zero: keeps table reads in-loop
#pragma unroll 1
        for (int rt = 0; rt < 4; rt++) {
            asm volatile("" : "+v"(zr));
            const int qz = quad + zr;
            const int wb = qz * 16;
            const half2v xp = __builtin_bit_cast(half2v, sXs[wv][rt * 16 + l15]);

            // layer-1 weights: quad-broadcast LDS reads (conflict-free)
            union { uint4 q[4]; uint u[16]; } W1L;
            union { float4 q[4]; float f[16]; } B1L;
#pragma unroll
            for (int i = 0; i < 4; i++) {
                W1L.q[i] = *(const uint4*)&w1tb[qz][4 * i];
                B1L.q[i] = *(const float4*)&b1tb[qz][4 * i];
            }

            union { half8v v; uint uu[4]; } B0, B1;
#pragma unroll
            for (int jj = 0; jj < 4; jj++) {
                const float t0 = tanh2(fdot2(xp, __builtin_bit_cast(half2v, W1L.u[2 * jj]),     B1L.f[2 * jj]));
                const float t1 = tanh2(fdot2(xp, __builtin_bit_cast(half2v, W1L.u[2 * jj + 1]), B1L.f[2 * jj + 1]));
                const float t2 = tanh2(fdot2(xp, __builtin_bit_cast(half2v, W1L.u[8 + 2 * jj]),     B1L.f[8 + 2 * jj]));
                const float t3 = tanh2(fdot2(xp, __builtin_bit_cast(half2v, W1L.u[8 + 2 * jj + 1]), B1L.f[8 + 2 * jj + 1]));
                B0.uu[jj] = __builtin_bit_cast(uint, pk(t0, t1));
                B1.uu[jj] = __builtin_bit_cast(uint, pk(t2, t3));
            }

            half2v sp = {_Float16(0.f), _Float16(0.f)};
            TSTEP(0, bfq[0], bfq[1]);
            TSTEP(1, bfq[2], bfq[3]);
            TSTEP(2, bfq[4], bfq[5]);
            TSTEP(3, bfq[6], bfq[7]);

            float s0 = (float)sp[0], s1 = (float)sp[1];
            s0 += SWZF(s0, 0x401F);
            s1 += SWZF(s1, 0x401F);
            s0 += __shfl_xor(s0, 32, 64);
            s1 += __shfl_xor(s1, 32, 64);
            if (quad == 0) {
                const float p = (s0 + b30c) * isg0;
                const float q = (s1 + b31c) * isg1;
                sGs[wv][rt * 16 + l15] = __builtin_bit_cast(uint, pk(p, q));
            }
        }
        // one drain per tile: B regs, uN and the PREVIOUS tile's atomics
        // are all >= one phase old here.
        asm volatile("s_waitcnt vmcnt(0) lgkmcnt(0)");
        __builtin_amdgcn_sched_barrier(0);

        // ---- phase 3: EP pair -> ONE u64 fixed-point atomic per pair ----
        {
            const int rb = lane & ~3;
            const int j0 = 2 * g;
            float a = 0.f, b = 0.f;
#pragma unroll
            for (int gp = 0; gp < 4; gp++) {
                const int rr = rb + gp;
                const half2v pq = __builtin_bit_cast(half2v, sGs[wv][rr]);
                const uint w0 = sPQ[j0 * 260 + pqb + rr];
                const uint w1 = sPQ[(j0 + 1) * 260 + pqb + rr];
                a = fdot2(pq, __builtin_bit_cast(half2v, w0), a);
                b = fdot2(pq, __builtin_bit_cast(half2v, w1), b);
            }
            const int ia = __float2int_rn(a * FSCALE);
            const int ib = __float2int_rn(b * FSCALE);
            const unsigned long long pkd =
                ((unsigned long long)(unsigned)ib << 32) | (unsigned)ia;
            atomicAdd(&F64[connT], pkd);
        }

        connT = connN; uT = uN; jacT = jacN; wvT = wvN;
    }
}

extern "C" void kernel_launch(void* const* d_in, const int* in_sizes, int n_in,
                              void* d_out, int out_size, void* d_ws, size_t ws_size,
                              hipStream_t stream) {
    const float* u           = (const float*)d_in[0];
    const float* B           = (const float*)d_in[1];
    const float* Jacc        = (const float*)d_in[2];
    const float* gp_w        = (const float*)d_in[3];
    const int*   conn        = (const int*)  d_in[4];
    const float* weight1     = (const float*)d_in[5];
    const float* scales_inp  = (const float*)d_in[6];
    const float* limits_inp  = (const float*)d_in[7];
    const float* scales_grad = (const float*)d_in[8];
    const float* limits_grad = (const float*)d_in[9];
    const float* W1          = (const float*)d_in[10];
    const float* b1          = (const float*)d_in[11];
    const float* W2          = (const float*)d_in[12];
    const float* b2          = (const float*)d_in[13];
    const float* W3          = (const float*)d_in[14];
    const float* b3          = (const float*)d_in[15];
    unsigned long long* F64 = (unsigned long long*)d_out;

    uint4* wt = (uint4*)d_ws;                       // 16 KB weight table
    float* u1 = (float*)((char*)d_ws + 16384);      // 2 MB premultiplied u
    const int can_premul = (ws_size >= 16384 + sizeof(float) * NDOF) ? 1 : 0;

    (void)hipMemsetAsync(d_out, 0, sizeof(float) * NDOF, stream);

    pack_weights<<<1, 64, 0, stream>>>(W2, wt);
    if (can_premul)
        premul_u<<<(NDOF / 4 + 255) / 256, 256, 0, stream>>>(u, weight1, u1);

    fem_force_kernel<<<NBLK, 256, 0, stream>>>(
        can_premul ? u1 : u, B, Jacc, gp_w, conn, weight1,
        scales_inp, limits_inp, scales_grad, limits_grad,
        W1, b1, b2, W3, b3, wt, can_premul, F64);

    convert_F<<<(NNODE + 255) / 256, 256, 0, stream>>>(F64);
}